// Round 1
// baseline (65.619 us; speedup 1.0000x reference)
//
#include <hip/hip_runtime.h>

#define BB 32
#define HH 256
#define WW 256
#define CC 4
#define KH 5
#define KW 5
#define FF 8
#define HO (HH - KH + 1)   // 252
#define WO (WW - KW + 1)   // 252

__global__ __launch_bounds__(256) void erosion2d_kernel(
    const float* __restrict__ x,
    const float* __restrict__ k,
    float* __restrict__ out)
{
    const int total = BB * HO * WO;
    int tid = blockIdx.x * blockDim.x + threadIdx.x;
    if (tid >= total) return;

    // Decompose tid -> (b, y, xo); tid is row-major over (B, HO, WO),
    // which exactly matches the output layout (f contiguous innermost).
    int b   = tid / (HO * WO);
    int rem = tid - b * (HO * WO);
    int y   = rem / WO;
    int xo  = rem - y * WO;

    const float* xb = x + (((size_t)b * HH + y) * WW + xo) * CC;

    float acc[FF];
#pragma unroll
    for (int f = 0; f < FF; ++f) acc[f] = 3.0e38f;

#pragma unroll
    for (int dy = 0; dy < KH; ++dy) {
#pragma unroll
        for (int dx = 0; dx < KW; ++dx) {
            // One input pixel: 4 channels, 16B aligned.
            const float4 px = *reinterpret_cast<const float4*>(xb + (dy * WW + dx) * CC);
            // Kernel block for this tap: 32 contiguous floats (c-major, f inner).
            // All indices are compile-time constants relative to a uniform
            // pointer -> scalar loads (s_load_dwordx16).
            const float* kp = k + ((dy * KW + dx) * CC) * FF;
#pragma unroll
            for (int f = 0; f < FF; ++f) {
                float d0 = px.x - kp[0 * FF + f];
                float d1 = px.y - kp[1 * FF + f];
                float d2 = px.z - kp[2 * FF + f];
                float d3 = px.w - kp[3 * FF + f];
                // Balanced min tree -> v_min3_f32 fusion.
                acc[f] = fminf(fminf(acc[f], fminf(d0, d1)), fminf(d2, d3));
            }
        }
    }

    float* op = out + (size_t)tid * FF;
    float4 o0 = make_float4(acc[0], acc[1], acc[2], acc[3]);
    float4 o1 = make_float4(acc[4], acc[5], acc[6], acc[7]);
    *reinterpret_cast<float4*>(op)     = o0;
    *reinterpret_cast<float4*>(op + 4) = o1;
}

extern "C" void kernel_launch(void* const* d_in, const int* in_sizes, int n_in,
                              void* d_out, int out_size, void* d_ws, size_t ws_size,
                              hipStream_t stream) {
    const float* x = (const float*)d_in[0];
    const float* k = (const float*)d_in[1];
    float* out = (float*)d_out;

    const int total = BB * HO * WO;           // 2,032,128 output pixels
    const int block = 256;
    const int grid  = (total + block - 1) / block;  // 7938 blocks

    erosion2d_kernel<<<grid, block, 0, stream>>>(x, k, out);
}

// Round 3
// 64.532 us; speedup vs baseline: 1.0168x; 1.0168x over previous
//
#include <hip/hip_runtime.h>

#define BB 32
#define HH 256
#define WW 256
#define CC 4
#define KH 5
#define KW 5
#define FF 8
#define HO (HH - KH + 1)   // 252
#define WO (WW - KW + 1)   // 252
#define PX 2               // output pixels per thread (along x); WO % PX == 0
#define WOP (WO / PX)      // 126

typedef _Float16 h2     __attribute__((ext_vector_type(2)));
typedef __fp16   fp16x2 __attribute__((ext_vector_type(2)));

static __device__ __forceinline__ h2 pkrtz(float a, float b) {
    fp16x2 r = __builtin_amdgcn_cvt_pkrtz(a, b);
    return __builtin_bit_cast(h2, r);
}

// --- Kernel A: pre-pack the erosion kernel into f16 pairs in d_ws. ---
// Layout (dword index): [tap][f][pair], tap = dy*KW+dx, pair0=(c0,c1), pair1=(c2,c3).
// 400 dwords = 1600 B. Low half of each dword = even channel.
__global__ void pack_kernel(const float* __restrict__ k, unsigned int* __restrict__ kp)
{
    int i = blockIdx.x * blockDim.x + threadIdx.x;
    if (i >= KH * KW * FF * 2) return;        // 400
    int t = i >> 4;          // tap (dy*KW+dx)
    int r = i & 15;
    int f = r >> 1;
    int p = r & 1;           // channel pair
    float a = k[(t * CC + 2 * p + 0) * FF + f];
    float b = k[(t * CC + 2 * p + 1) * FF + f];
    kp[i] = __builtin_bit_cast(unsigned int, pkrtz(a, b));
}

// --- Kernel B: main erosion, packed f16 over channel pairs. ---
__global__ __launch_bounds__(256) void erosion2d_f16(
    const float* __restrict__ x,
    const h2* __restrict__ k2,        // d_ws, layout above
    float* __restrict__ out)
{
    const int total = BB * HO * WOP;
    int tid = blockIdx.x * blockDim.x + threadIdx.x;
    if (tid >= total) return;

    int b   = tid / (HO * WOP);
    int rem = tid - b * (HO * WOP);
    int y   = rem / WOP;
    int xo  = (rem - y * WOP) * PX;

    const float* xb = x + (((size_t)b * HH + y) * WW + xo) * CC;

    h2 acc[PX][FF];
    const h2 big = { (_Float16)65504.0f, (_Float16)65504.0f };
#pragma unroll
    for (int p = 0; p < PX; ++p)
#pragma unroll
        for (int f = 0; f < FF; ++f)
            acc[p][f] = big;

#pragma unroll
    for (int dy = 0; dy < KH; ++dy) {
#pragma unroll
        for (int dxx = 0; dxx < KW + PX - 1; ++dxx) {   // 6 input columns serve 2 outputs
            const float4 px = *reinterpret_cast<const float4*>(xb + (dy * WW + dxx) * CC);
            const h2 p01 = pkrtz(px.x, px.y);
            const h2 p23 = pkrtz(px.z, px.w);
#pragma unroll
            for (int p = 0; p < PX; ++p) {
                const int dx = dxx - p;
                if (dx < 0 || dx >= KW) continue;
                // Wave-uniform kernel operands -> scalar loads (SMEM),
                // consumed as the SGPR operand of v_pk_*_f16.
                const h2* kt = k2 + ((dy * KW + dx) * FF) * 2;
#pragma unroll
                for (int f = 0; f < FF; ++f) {
                    h2 d01 = p01 - kt[f * 2 + 0];
                    h2 d23 = p23 - kt[f * 2 + 1];
                    acc[p][f] = __builtin_elementwise_min(
                        acc[p][f], __builtin_elementwise_min(d01, d23));
                }
            }
        }
    }

#pragma unroll
    for (int p = 0; p < PX; ++p) {
        float r[FF];
#pragma unroll
        for (int f = 0; f < FF; ++f)
            r[f] = fminf((float)acc[p][f][0], (float)acc[p][f][1]);
        float* op = out + ((size_t)tid * PX + p) * FF;
        *reinterpret_cast<float4*>(op)     = make_float4(r[0], r[1], r[2], r[3]);
        *reinterpret_cast<float4*>(op + 4) = make_float4(r[4], r[5], r[6], r[7]);
    }
}

extern "C" void kernel_launch(void* const* d_in, const int* in_sizes, int n_in,
                              void* d_out, int out_size, void* d_ws, size_t ws_size,
                              hipStream_t stream) {
    const float* x = (const float*)d_in[0];
    const float* k = (const float*)d_in[1];
    float* out = (float*)d_out;

    // Pack kernel weights to f16 in workspace (1600 B; rewritten every launch).
    pack_kernel<<<2, 256, 0, stream>>>(k, (unsigned int*)d_ws);

    const int total = BB * HO * WOP;                 // 1,016,064 threads
    const int block = 256;
    const int grid  = (total + block - 1) / block;   // 3969 blocks
    erosion2d_f16<<<grid, block, 0, stream>>>(x, (const h2*)d_ws, out);
}